// Round 14
// baseline (216.138 us; speedup 1.0000x reference)
//
#include <hip/hip_runtime.h>

#define NN 100000
#define EE 1600000
#define FIN 128
#define FHID 64

#define BSH 7                       // bucket = node >> 7 (128 nodes/bucket)
#define NB  ((NN + 127) / 128)      // 782 buckets
#define CAP 3072                    // max edges/bucket (mean 2048, +22 sigma)
#define BIN_BLOCKS 256
#define BIN_EPT 8
#define BIN_EPB (1024 * BIN_EPT)    // 8192 edges/block

typedef union { _Float16 h[4]; uint2 u; } H4;
typedef union { _Float16 h[8]; uint4 u; } H8;

__global__ void k_zero_int(int* __restrict__ p, int n) {
    int i = blockIdx.x * blockDim.x + threadIdx.x;
    if (i < n) p[i] = 0;
}

// ---------- pass 1: bin edges by dest bucket; dense chunk writes of
//            packed (c:17 | r:17) records ----------
__global__ __launch_bounds__(1024) void k_bin(const int* __restrict__ row,
                                              const int* __restrict__ col,
                                              int* __restrict__ bcnt,
                                              unsigned long long* __restrict__ rec) {
    __shared__ int hist[NB];
    __shared__ int base[NB];
    int tid = threadIdx.x;
    for (int i = tid; i < NB; i += 1024) hist[i] = 0;
    __syncthreads();
    int e0 = blockIdx.x * BIN_EPB;
    int b[BIN_EPT];
    int rnk[BIN_EPT];
    unsigned long long pk[BIN_EPT];
#pragma unroll
    for (int j = 0; j < BIN_EPT; ++j) {
        int e = e0 + j * 1024 + tid;
        b[j] = -1;
        if (e < EE) {
            int c = col[e];
            int r = row[e];
            b[j] = c >> BSH;
            pk[j] = ((unsigned long long)(unsigned)c << 17) | (unsigned)r;
            rnk[j] = atomicAdd(&hist[b[j]], 1);
        }
    }
    __syncthreads();
    for (int i = tid; i < NB; i += 1024) {
        int h = hist[i];
        base[i] = h ? atomicAdd(&bcnt[i], h) : 0;
    }
    __syncthreads();
#pragma unroll
    for (int j = 0; j < BIN_EPT; ++j) {
        if (b[j] >= 0) {
            int p = base[b[j]] + rnk[j];
            if (p < CAP) rec[(size_t)b[j] * CAP + p] = pk[j];
        }
    }
}

// ---------- pass 2: per-bucket CSR finalize (fixed stride b*CAP);
//            emits csr_src, starts, degi, dinv ----------
__global__ __launch_bounds__(256) void k_csr(const int* __restrict__ bcnt,
                                             const unsigned long long* __restrict__ rec,
                                             int* __restrict__ csr_src,
                                             int* __restrict__ starts,
                                             int* __restrict__ degi,
                                             float* __restrict__ dinv) {
    __shared__ unsigned short rank[CAP];   // 6 KB
    __shared__ int nh[128];
    __shared__ int ns[128];
    __shared__ int nsx[128];
    int b = blockIdx.x;
    int tid = threadIdx.x;
    int cnt = bcnt[b];
    if (cnt > CAP) cnt = CAP;
    int gb = b * CAP;
    const unsigned long long* r = rec + (size_t)b * CAP;
    if (tid < 128) nh[tid] = 0;
    __syncthreads();
    for (int i = tid; i < cnt; i += 256) {
        int c = (int)(r[i] >> 17);
        int cl = c - (b << BSH);
        rank[i] = (unsigned short)atomicAdd(&nh[cl], 1);
    }
    __syncthreads();
    if (tid < 128) ns[tid] = nh[tid];
    __syncthreads();
    for (int off = 1; off < 128; off <<= 1) {
        int x = 0;
        if (tid < 128 && tid >= off) x = ns[tid - off];
        __syncthreads();
        if (tid < 128) ns[tid] += x;
        __syncthreads();
    }
    if (tid < 128) {
        int excl = ns[tid] - nh[tid];
        nsx[tid] = excl;
        int n = (b << BSH) + tid;
        if (n < NN) {
            starts[n] = gb + excl;
            degi[n] = nh[tid];
            dinv[n] = rsqrtf((float)(nh[tid] + 1));   // +1 self-loop
        }
    }
    __syncthreads();
    for (int i = tid; i < cnt; i += 256) {
        unsigned long long rv = r[i];
        int c = (int)(rv >> 17);
        int cl = c - (b << BSH);
        csr_src[gb + nsx[cl] + (int)rank[i]] = (int)(rv & 0x1FFFF);
    }
}

// ---------- GEMM1: hs16 = fp16((x @ W1) * dinv) ----------
// 512 threads = 8 waves; wave w computes cols [w*8, w*8+8) for 64 nodes
// (lane = node) -> 4 blocks x 8 waves = 32 waves/CU (max occupancy).
// LDS dword perm(c) = (c&3)*32 + (c>>2): conflict-free staging + reads.
#define XPAD 129
__global__ __launch_bounds__(512) void k_gemm1(const float* __restrict__ x,
                                               const float* __restrict__ W1,
                                               const float* __restrict__ dinv,
                                               uint4* __restrict__ hs16) {
    __shared__ float xl[64 * XPAD];  // 33 KB
    int tid = threadIdx.x;
    int n0 = blockIdx.x * 64;
    const float4* x4 = reinterpret_cast<const float4*>(x);
#pragma unroll
    for (int i = 0; i < 4; ++i) {
        int idx = i * 512 + tid;     // 2048 float4 slots = 64 rows x 32
        int row = idx >> 5;
        int k4 = idx & 31;
        float4 v = {0.f, 0.f, 0.f, 0.f};
        if (n0 + row < NN) v = x4[(size_t)(n0 + row) * 32 + k4];
        float* p = &xl[row * XPAD + k4];   // perm(k4*4+j) = j*32 + k4
        p[0] = v.x; p[32] = v.y; p[64] = v.z; p[96] = v.w;
    }
    __syncthreads();

    int wv = __builtin_amdgcn_readfirstlane(tid >> 6);   // 0..7
    int lane = tid & 63;
    float acc[8];
#pragma unroll
    for (int c = 0; c < 8; ++c) acc[c] = 0.f;
    const float* Wb = W1 + wv * 8;
    const float* xrow = &xl[lane * XPAD];
#pragma unroll 8
    for (int k = 0; k < FIN; ++k) {
        float xk = xrow[((k & 3) << 5) | (k >> 2)];
        const float* wr = Wb + k * FHID;
#pragma unroll
        for (int c = 0; c < 8; ++c) acc[c] = fmaf(xk, wr[c], acc[c]);
    }

    int node = n0 + lane;
    if (node < NN) {
        float dn = dinv[node];
        H8 pk;
#pragma unroll
        for (int c = 0; c < 8; ++c) pk.h[c] = (_Float16)(acc[c] * dn);
        hs16[(size_t)node * 8 + wv] = pk.u;
    }
}

// ---------- GEMM2: hs16 = fp16((y1 @ W2) * dinv), y1 already relu'd fp16 ----------
#define X2PAD 65
typedef union { _Float16 h[16]; uint4 u[2]; } H16;
__global__ __launch_bounds__(256) void k_gemm2(const uint2* __restrict__ y1,
                                               const float* __restrict__ W2,
                                               const float* __restrict__ dinv,
                                               uint4* __restrict__ hs16) {
    __shared__ float al[64 * X2PAD];  // 16.6 KB
    int tid = threadIdx.x;
    int n0 = blockIdx.x * 64;
#pragma unroll
    for (int i = 0; i < 4; ++i) {
        int idx = i * 256 + tid;     // 1024 uint2 slots = 64 rows x 16
        int rw = idx >> 4;
        int k4 = idx & 15;
        float4 v = {0.f, 0.f, 0.f, 0.f};
        if (n0 + rw < NN) {
            H4 t;
            t.u = y1[(size_t)(n0 + rw) * 16 + k4];
            v.x = (float)t.h[0]; v.y = (float)t.h[1];
            v.z = (float)t.h[2]; v.w = (float)t.h[3];
        }
        float* p = &al[rw * X2PAD + k4];  // perm(k4*4+j) = j*16 + k4
        p[0] = v.x; p[16] = v.y; p[32] = v.z; p[48] = v.w;
    }
    __syncthreads();

    int wv = __builtin_amdgcn_readfirstlane(tid >> 6);
    int lane = tid & 63;
    float acc[16];
#pragma unroll
    for (int c = 0; c < 16; ++c) acc[c] = 0.f;
    const float* Wb = W2 + wv * 16;
    const float* arow = &al[lane * X2PAD];
#pragma unroll 8
    for (int k = 0; k < FHID; ++k) {
        float xk = arow[((k & 3) << 4) | (k >> 2)];
        const float* wr = Wb + k * FHID;
#pragma unroll
        for (int c = 0; c < 16; ++c) acc[c] = fmaf(xk, wr[c], acc[c]);
    }

    int node = n0 + lane;
    if (node < NN) {
        float dn = dinv[node];
        H16 pk;
#pragma unroll
        for (int c = 0; c < 16; ++c) pk.h[c] = (_Float16)(acc[c] * dn);
        hs16[(size_t)node * 8 + wv * 2] = pk.u[0];
        hs16[(size_t)node * 8 + wv * 2 + 1] = pk.u[1];
    }
}

// ---------- CSR aggregation: y[n] = fp16(relu(dinv[n]*(h[n]+sum h[src]) + bias)) ----------
// One wave per node. Indices csr_src[s+lane] preloaded in ONE coalesced load,
// broadcast via __shfl -> gathers issue with no interleaved address loads.
__global__ __launch_bounds__(256) void k_gath(const int* __restrict__ starts,
                                              const int* __restrict__ degi,
                                              const int* __restrict__ csr_src,
                                              const float* __restrict__ dinv,
                                              const uint4* __restrict__ hIn,
                                              const float* __restrict__ bias,
                                              uint4* __restrict__ yOut) {
    int wave = threadIdx.x >> 6;
    int lane = threadIdx.x & 63;
    int g = lane >> 3;        // row-group 0..7
    int fl = lane & 7;        // 16B chunk 0..7
    int n = blockIdx.x * 4 + wave;
    if (n >= NN) return;
    int s = starts[n];
    int d = degi[n];
    int idx = (lane < d) ? csr_src[s + lane] : 0;   // one coalesced load
    float a[8];
    H8 pk;
    if (g == 0) {             // self term
        pk.u = hIn[(size_t)n * 8 + fl];
#pragma unroll
        for (int j = 0; j < 8; ++j) a[j] = (float)pk.h[j];
    } else {
#pragma unroll
        for (int j = 0; j < 8; ++j) a[j] = 0.f;
    }
    int dc = d < 64 ? d : 64;
    for (int k = g; k < dc; k += 8) {
        int r = __shfl(idx, k);
        H8 v;
        v.u = hIn[(size_t)r * 8 + fl];
#pragma unroll
        for (int j = 0; j < 8; ++j) a[j] += (float)v.h[j];
    }
    for (int k = 64 + g; k < d; k += 8) {   // rare (deg>64) tail
        int r = csr_src[s + k];
        H8 v;
        v.u = hIn[(size_t)r * 8 + fl];
#pragma unroll
        for (int j = 0; j < 8; ++j) a[j] += (float)v.h[j];
    }
#pragma unroll
    for (int j = 0; j < 8; ++j) {
        a[j] += __shfl_xor(a[j], 8);
        a[j] += __shfl_xor(a[j], 16);
        a[j] += __shfl_xor(a[j], 32);
    }
    if (g == 0) {
        float dn = dinv[n];
        float4 b0 = reinterpret_cast<const float4*>(bias)[fl * 2];
        float4 b1 = reinterpret_cast<const float4*>(bias)[fl * 2 + 1];
        H8 o;
        o.h[0] = (_Float16)fmaxf(fmaf(a[0], dn, b0.x), 0.f);
        o.h[1] = (_Float16)fmaxf(fmaf(a[1], dn, b0.y), 0.f);
        o.h[2] = (_Float16)fmaxf(fmaf(a[2], dn, b0.z), 0.f);
        o.h[3] = (_Float16)fmaxf(fmaf(a[3], dn, b0.w), 0.f);
        o.h[4] = (_Float16)fmaxf(fmaf(a[4], dn, b1.x), 0.f);
        o.h[5] = (_Float16)fmaxf(fmaf(a[5], dn, b1.y), 0.f);
        o.h[6] = (_Float16)fmaxf(fmaf(a[6], dn, b1.z), 0.f);
        o.h[7] = (_Float16)fmaxf(fmaf(a[7], dn, b1.w), 0.f);
        yOut[(size_t)n * 8 + fl] = o.u;
    }
}

// ---------- link prediction: 64-edge batches/wave; indices preloaded
//            coalesced and broadcast via shfl; 8 edges x 8 lanes per iter ----------
__global__ __launch_bounds__(256) void k_link(const int* __restrict__ row0,
                                              const int* __restrict__ col0,
                                              const uint4* __restrict__ y16,
                                              const float* __restrict__ Wout,
                                              const float* __restrict__ bout,
                                              float* __restrict__ out) {
    int wid = blockIdx.x * 4 + (threadIdx.x >> 6);
    int lane = threadIdx.x & 63;
    int sub = lane >> 3;      // edge slot within iteration 0..7
    int fl = lane & 7;
    float4 w0 = reinterpret_cast<const float4*>(Wout)[fl * 2];
    float4 w1 = reinterpret_cast<const float4*>(Wout)[fl * 2 + 1];
    float wv[8] = {w0.x, w0.y, w0.z, w0.w, w1.x, w1.y, w1.z, w1.w};
    float bout0 = bout[0];
    const int NBATCH = EE / 64;    // 25000
    int stride = gridDim.x * 4;
    for (int q = wid; q < NBATCH; q += stride) {
        int e0 = q * 64;
        int r64 = row0[e0 + lane];   // one coalesced load each
        int c64 = col0[e0 + lane];
#pragma unroll
        for (int it = 0; it < 8; ++it) {
            int k = it * 8 + sub;
            int r = __shfl(r64, k);
            int c = __shfl(c64, k);
            H8 hr, hc;
            hr.u = y16[(size_t)r * 8 + fl];
            hc.u = y16[(size_t)c * 8 + fl];
            float p = 0.f;
#pragma unroll
            for (int j = 0; j < 8; ++j)
                p = fmaf((float)hr.h[j], (float)hc.h[j] * wv[j], p);
            p += __shfl_xor(p, 1);
            p += __shfl_xor(p, 2);
            p += __shfl_xor(p, 4);
            if (fl == 0) out[e0 + k] = p + bout0;
        }
    }
}

extern "C" void kernel_launch(void* const* d_in, const int* in_sizes, int n_in,
                              void* d_out, int out_size, void* d_ws, size_t ws_size,
                              hipStream_t stream) {
    const float* x    = (const float*)d_in[0];
    const int*   ei   = (const int*)d_in[1];   // int64 in reference -> int32 here
    const float* W1   = (const float*)d_in[2];
    const float* b1   = (const float*)d_in[3];
    const float* W2   = (const float*)d_in[4];
    const float* b2   = (const float*)d_in[5];
    const float* Wout = (const float*)d_in[6];
    const float* bout = (const float*)d_in[7];
    const int*   row0 = ei;        // edge_index[0] (source)
    const int*   col0 = ei + EE;   // edge_index[1] (destination)

    char* ws = (char*)d_ws;
    auto align = [](size_t v) { return (v + 255) / 256 * 256; };
    const size_t nInt = align((size_t)NN * 4);
    float* dinv    = (float*)ws;                 ws += nInt;
    int*   degi    = (int*)ws;                   ws += nInt;
    int*   starts  = (int*)ws;                   ws += nInt;
    int*   bcnt    = (int*)ws;                   ws += align((size_t)NB * 4);
    int*   csr_src = (int*)ws;                   ws += align((size_t)NB * CAP * 4);
    uint4* bufH    = (uint4*)ws;                 ws += align((size_t)NN * FHID * 2);
    uint4* bufY    = (uint4*)ws;                 ws += align((size_t)NN * FHID * 2);
    // rec (19.2 MB) aliases bufH+bufY (25.6 MB): dead before k_gemm1 writes bufH
    unsigned long long* rec = (unsigned long long*)bufH;
    float* out = (float*)d_out;

    const int nTiles = (NN + 63) / 64;  // 1563

    // CSR build: zero -> bin -> finalize (fixed stride; no scan kernel)
    k_zero_int<<<(NB + 255) / 256, 256, 0, stream>>>(bcnt, NB);
    k_bin<<<BIN_BLOCKS, 1024, 0, stream>>>(row0, col0, bcnt, rec);
    k_csr<<<NB, 256, 0, stream>>>(bcnt, rec, csr_src, starts, degi, dinv);

    // layer 1: hs1 = (x@W1)*dinv ; y1 = relu(dinv*gather(hs1) + b1)
    k_gemm1<<<nTiles, 512, 0, stream>>>(x, W1, dinv, bufH);
    k_gath<<<(NN + 3) / 4, 256, 0, stream>>>(starts, degi, csr_src, dinv, bufH, b1, bufY);

    // layer 2: hs2 = (y1@W2)*dinv ; y2 = relu(dinv*gather(hs2) + b2)
    k_gemm2<<<nTiles, 256, 0, stream>>>((const uint2*)bufY, W2, dinv, bufH);
    k_gath<<<(NN + 3) / 4, 256, 0, stream>>>(starts, degi, csr_src, dinv, bufH, b2, bufY);

    // edge scoring in original edge order (coalesced reads + writes)
    k_link<<<2048, 256, 0, stream>>>(row0, col0, bufY, Wout, bout, out);
}

// Round 15
// 202.382 us; speedup vs baseline: 1.0680x; 1.0680x over previous
//
#include <hip/hip_runtime.h>

#define NN 100000
#define EE 1600000
#define FIN 128
#define FHID 64

#define BSH 7                       // bucket = node >> 7 (128 nodes/bucket)
#define NB  ((NN + 127) / 128)      // 782 buckets
#define CAP 3072                    // max edges/bucket (mean 2048, +22 sigma)
#define BIN_BLOCKS 256
#define BIN_EPT 8
#define BIN_EPB (1024 * BIN_EPT)    // 8192 edges/block

typedef union { _Float16 h[4]; uint2 u; } H4;
typedef union { _Float16 h[8]; uint4 u; } H8;

// ---------- pass 1: bin edges by dest bucket; dense chunk writes of
//            packed (c:17 | r:17) records ----------
__global__ __launch_bounds__(1024) void k_bin(const int* __restrict__ row,
                                              const int* __restrict__ col,
                                              int* __restrict__ bcnt,
                                              unsigned long long* __restrict__ rec) {
    __shared__ int hist[NB];
    __shared__ int base[NB];
    int tid = threadIdx.x;
    for (int i = tid; i < NB; i += 1024) hist[i] = 0;
    __syncthreads();
    int e0 = blockIdx.x * BIN_EPB;
    int b[BIN_EPT];
    int rnk[BIN_EPT];
    unsigned long long pk[BIN_EPT];
#pragma unroll
    for (int j = 0; j < BIN_EPT; ++j) {
        int e = e0 + j * 1024 + tid;
        b[j] = -1;
        if (e < EE) {
            int c = col[e];
            int r = row[e];
            b[j] = c >> BSH;
            pk[j] = ((unsigned long long)(unsigned)c << 17) | (unsigned)r;
            rnk[j] = atomicAdd(&hist[b[j]], 1);
        }
    }
    __syncthreads();
    for (int i = tid; i < NB; i += 1024) {
        int h = hist[i];
        base[i] = h ? atomicAdd(&bcnt[i], h) : 0;
    }
    __syncthreads();
#pragma unroll
    for (int j = 0; j < BIN_EPT; ++j) {
        if (b[j] >= 0) {
            int p = base[b[j]] + rnk[j];
            if (p < CAP) rec[(size_t)b[j] * CAP + p] = pk[j];
        }
    }
}

// ---------- pass 2: per-bucket CSR finalize (fixed stride b*CAP);
//            emits csr_src, starts, degi, dinv ----------
__global__ __launch_bounds__(256) void k_csr(const int* __restrict__ bcnt,
                                             const unsigned long long* __restrict__ rec,
                                             int* __restrict__ csr_src,
                                             int* __restrict__ starts,
                                             int* __restrict__ degi,
                                             float* __restrict__ dinv) {
    __shared__ unsigned short rank[CAP];   // 6 KB
    __shared__ int nh[128];
    __shared__ int ns[128];
    __shared__ int nsx[128];
    int b = blockIdx.x;
    int tid = threadIdx.x;
    int cnt = bcnt[b];
    if (cnt > CAP) cnt = CAP;
    int gb = b * CAP;
    const unsigned long long* r = rec + (size_t)b * CAP;
    if (tid < 128) nh[tid] = 0;
    __syncthreads();
    for (int i = tid; i < cnt; i += 256) {
        int c = (int)(r[i] >> 17);
        int cl = c - (b << BSH);
        rank[i] = (unsigned short)atomicAdd(&nh[cl], 1);
    }
    __syncthreads();
    if (tid < 128) ns[tid] = nh[tid];
    __syncthreads();
    for (int off = 1; off < 128; off <<= 1) {
        int x = 0;
        if (tid < 128 && tid >= off) x = ns[tid - off];
        __syncthreads();
        if (tid < 128) ns[tid] += x;
        __syncthreads();
    }
    if (tid < 128) {
        int excl = ns[tid] - nh[tid];
        nsx[tid] = excl;
        int n = (b << BSH) + tid;
        if (n < NN) {
            starts[n] = gb + excl;
            degi[n] = nh[tid];
            dinv[n] = rsqrtf((float)(nh[tid] + 1));   // +1 self-loop
        }
    }
    __syncthreads();
    for (int i = tid; i < cnt; i += 256) {
        unsigned long long rv = r[i];
        int c = (int)(rv >> 17);
        int cl = c - (b << BSH);
        csr_src[gb + nsx[cl] + (int)rank[i]] = (int)(rv & 0x1FFFF);
    }
}

// ---------- GEMM1: hs16 = fp16((x @ W1) * dinv) ----------
// 512 threads = 8 waves; wave w computes cols [w*8, w*8+8) for 64 nodes
// (lane = node) -> 4 blocks x 8 waves = 32 waves/CU (max occupancy).
#define XPAD 129
__global__ __launch_bounds__(512) void k_gemm1(const float* __restrict__ x,
                                               const float* __restrict__ W1,
                                               const float* __restrict__ dinv,
                                               uint4* __restrict__ hs16) {
    __shared__ float xl[64 * XPAD];  // 33 KB
    int tid = threadIdx.x;
    int n0 = blockIdx.x * 64;
    const float4* x4 = reinterpret_cast<const float4*>(x);
#pragma unroll
    for (int i = 0; i < 4; ++i) {
        int idx = i * 512 + tid;     // 2048 float4 slots = 64 rows x 32
        int row = idx >> 5;
        int k4 = idx & 31;
        float4 v = {0.f, 0.f, 0.f, 0.f};
        if (n0 + row < NN) v = x4[(size_t)(n0 + row) * 32 + k4];
        float* p = &xl[row * XPAD + k4];   // perm(k4*4+j) = j*32 + k4
        p[0] = v.x; p[32] = v.y; p[64] = v.z; p[96] = v.w;
    }
    __syncthreads();

    int wv = __builtin_amdgcn_readfirstlane(tid >> 6);   // 0..7
    int lane = tid & 63;
    float acc[8];
#pragma unroll
    for (int c = 0; c < 8; ++c) acc[c] = 0.f;
    const float* Wb = W1 + wv * 8;
    const float* xrow = &xl[lane * XPAD];
#pragma unroll 8
    for (int k = 0; k < FIN; ++k) {
        float xk = xrow[((k & 3) << 5) | (k >> 2)];
        const float* wr = Wb + k * FHID;
#pragma unroll
        for (int c = 0; c < 8; ++c) acc[c] = fmaf(xk, wr[c], acc[c]);
    }

    int node = n0 + lane;
    if (node < NN) {
        float dn = dinv[node];
        H8 pk;
#pragma unroll
        for (int c = 0; c < 8; ++c) pk.h[c] = (_Float16)(acc[c] * dn);
        hs16[(size_t)node * 8 + wv] = pk.u;
    }
}

// ---------- GEMM2: hs16 = fp16((y1 @ W2) * dinv), y1 already relu'd fp16 ----------
#define X2PAD 65
typedef union { _Float16 h[16]; uint4 u[2]; } H16;
__global__ __launch_bounds__(256) void k_gemm2(const uint2* __restrict__ y1,
                                               const float* __restrict__ W2,
                                               const float* __restrict__ dinv,
                                               uint4* __restrict__ hs16) {
    __shared__ float al[64 * X2PAD];  // 16.6 KB
    int tid = threadIdx.x;
    int n0 = blockIdx.x * 64;
#pragma unroll
    for (int i = 0; i < 4; ++i) {
        int idx = i * 256 + tid;     // 1024 uint2 slots = 64 rows x 16
        int rw = idx >> 4;
        int k4 = idx & 15;
        float4 v = {0.f, 0.f, 0.f, 0.f};
        if (n0 + rw < NN) {
            H4 t;
            t.u = y1[(size_t)(n0 + rw) * 16 + k4];
            v.x = (float)t.h[0]; v.y = (float)t.h[1];
            v.z = (float)t.h[2]; v.w = (float)t.h[3];
        }
        float* p = &al[rw * X2PAD + k4];  // perm(k4*4+j) = j*16 + k4
        p[0] = v.x; p[16] = v.y; p[32] = v.z; p[48] = v.w;
    }
    __syncthreads();

    int wv = __builtin_amdgcn_readfirstlane(tid >> 6);
    int lane = tid & 63;
    float acc[16];
#pragma unroll
    for (int c = 0; c < 16; ++c) acc[c] = 0.f;
    const float* Wb = W2 + wv * 16;
    const float* arow = &al[lane * X2PAD];
#pragma unroll 8
    for (int k = 0; k < FHID; ++k) {
        float xk = arow[((k & 3) << 4) | (k >> 2)];
        const float* wr = Wb + k * FHID;
#pragma unroll
        for (int c = 0; c < 16; ++c) acc[c] = fmaf(xk, wr[c], acc[c]);
    }

    int node = n0 + lane;
    if (node < NN) {
        float dn = dinv[node];
        H16 pk;
#pragma unroll
        for (int c = 0; c < 16; ++c) pk.h[c] = (_Float16)(acc[c] * dn);
        hs16[(size_t)node * 8 + wv * 2] = pk.u[0];
        hs16[(size_t)node * 8 + wv * 2 + 1] = pk.u[1];
    }
}

// ---------- CSR aggregation: y[n] = fp16(relu(dinv[n]*(h[n]+sum h[src]) + bias)) ----------
// One 8-lane GROUP per node (8 nodes/wave): per-feature sums stay inside the
// group -> NO cross-group reduce, epilogue on all lanes. Indices preloaded
// 24-deep (coalesced) and broadcast via intra-group shfl; full-8 chunks
// unrolled so 8 gathers issue back-to-back.
#define GCHUNK8(IDXREG)                                                     \
    {                                                                       \
        H8 v0, v1, v2, v3, v4, v5, v6, v7;                                  \
        v0.u = hIn[(size_t)__shfl(IDXREG, base + 0) * 8 + fl];              \
        v1.u = hIn[(size_t)__shfl(IDXREG, base + 1) * 8 + fl];              \
        v2.u = hIn[(size_t)__shfl(IDXREG, base + 2) * 8 + fl];              \
        v3.u = hIn[(size_t)__shfl(IDXREG, base + 3) * 8 + fl];              \
        v4.u = hIn[(size_t)__shfl(IDXREG, base + 4) * 8 + fl];              \
        v5.u = hIn[(size_t)__shfl(IDXREG, base + 5) * 8 + fl];              \
        v6.u = hIn[(size_t)__shfl(IDXREG, base + 6) * 8 + fl];              \
        v7.u = hIn[(size_t)__shfl(IDXREG, base + 7) * 8 + fl];              \
        _Pragma("unroll")                                                   \
        for (int j = 0; j < 8; ++j)                                         \
            a[j] += ((float)v0.h[j] + (float)v1.h[j]) +                     \
                    ((float)v2.h[j] + (float)v3.h[j]) +                     \
                    ((float)v4.h[j] + (float)v5.h[j]) +                     \
                    ((float)v6.h[j] + (float)v7.h[j]);                      \
    }

__global__ __launch_bounds__(256) void k_gath(const int* __restrict__ starts,
                                              const int* __restrict__ degi,
                                              const int* __restrict__ csr_src,
                                              const float* __restrict__ dinv,
                                              const uint4* __restrict__ hIn,
                                              const float* __restrict__ bias,
                                              uint4* __restrict__ yOut) {
    int wave = threadIdx.x >> 6;
    int lane = threadIdx.x & 63;
    int g = lane >> 3;        // group = node slot 0..7
    int fl = lane & 7;        // 16B chunk 0..7
    int base = lane & 56;     // g*8 (shfl source base within wave)
    int n = blockIdx.x * 32 + wave * 8 + g;
    if (n >= NN) return;
    int s = starts[n];
    int d = degi[n];
    // preload up to 24 indices (covers ~98% of Poisson(16) nodes fully)
    int ia = (fl < d)      ? csr_src[s + fl]      : 0;
    int ib = (8 + fl < d)  ? csr_src[s + 8 + fl]  : 0;
    int ic = (16 + fl < d) ? csr_src[s + 16 + fl] : 0;
    float a[8];
    H8 pk;
    pk.u = hIn[(size_t)n * 8 + fl];   // self term
#pragma unroll
    for (int j = 0; j < 8; ++j) a[j] = (float)pk.h[j];

    int k = 0;
    if (d >= 8)  { GCHUNK8(ia); k = 8; }
    if (d >= 16) { GCHUNK8(ib); k = 16; }
    if (d >= 24) { GCHUNK8(ic); k = 24; }
    // leftover inside preloaded registers ([k, min(d,24)))
    int lim = d < 24 ? d : 24;
    for (; k < lim; ++k) {
        int k8 = k >> 3;
        int src = (k8 == 0) ? ia : ((k8 == 1) ? ib : ic);
        H8 v;
        v.u = hIn[(size_t)__shfl(src, base + (k & 7)) * 8 + fl];
#pragma unroll
        for (int j = 0; j < 8; ++j) a[j] += (float)v.h[j];
    }
    for (; k < d; ++k) {              // rare deg>24 tail: direct index load
        H8 v;
        v.u = hIn[(size_t)csr_src[s + k] * 8 + fl];
#pragma unroll
        for (int j = 0; j < 8; ++j) a[j] += (float)v.h[j];
    }

    float dn = dinv[n];
    float4 b0 = reinterpret_cast<const float4*>(bias)[fl * 2];
    float4 b1 = reinterpret_cast<const float4*>(bias)[fl * 2 + 1];
    H8 o;
    o.h[0] = (_Float16)fmaxf(fmaf(a[0], dn, b0.x), 0.f);
    o.h[1] = (_Float16)fmaxf(fmaf(a[1], dn, b0.y), 0.f);
    o.h[2] = (_Float16)fmaxf(fmaf(a[2], dn, b0.z), 0.f);
    o.h[3] = (_Float16)fmaxf(fmaf(a[3], dn, b0.w), 0.f);
    o.h[4] = (_Float16)fmaxf(fmaf(a[4], dn, b1.x), 0.f);
    o.h[5] = (_Float16)fmaxf(fmaf(a[5], dn, b1.y), 0.f);
    o.h[6] = (_Float16)fmaxf(fmaf(a[6], dn, b1.z), 0.f);
    o.h[7] = (_Float16)fmaxf(fmaf(a[7], dn, b1.w), 0.f);
    yOut[(size_t)n * 8 + fl] = o.u;
}

// ---------- link prediction: 64-edge batches/wave; indices preloaded
//            coalesced and broadcast via shfl; 8 edges x 8 lanes per iter ----------
__global__ __launch_bounds__(256) void k_link(const int* __restrict__ row0,
                                              const int* __restrict__ col0,
                                              const uint4* __restrict__ y16,
                                              const float* __restrict__ Wout,
                                              const float* __restrict__ bout,
                                              float* __restrict__ out) {
    int wid = blockIdx.x * 4 + (threadIdx.x >> 6);
    int lane = threadIdx.x & 63;
    int sub = lane >> 3;      // edge slot within iteration 0..7
    int fl = lane & 7;
    float4 w0 = reinterpret_cast<const float4*>(Wout)[fl * 2];
    float4 w1 = reinterpret_cast<const float4*>(Wout)[fl * 2 + 1];
    float wv[8] = {w0.x, w0.y, w0.z, w0.w, w1.x, w1.y, w1.z, w1.w};
    float bout0 = bout[0];
    const int NBATCH = EE / 64;    // 25000
    int stride = gridDim.x * 4;
    for (int q = wid; q < NBATCH; q += stride) {
        int e0 = q * 64;
        int r64 = row0[e0 + lane];   // one coalesced load each
        int c64 = col0[e0 + lane];
#pragma unroll
        for (int it = 0; it < 8; ++it) {
            int k = it * 8 + sub;
            int r = __shfl(r64, k);
            int c = __shfl(c64, k);
            H8 hr, hc;
            hr.u = y16[(size_t)r * 8 + fl];
            hc.u = y16[(size_t)c * 8 + fl];
            float p = 0.f;
#pragma unroll
            for (int j = 0; j < 8; ++j)
                p = fmaf((float)hr.h[j], (float)hc.h[j] * wv[j], p);
            p += __shfl_xor(p, 1);
            p += __shfl_xor(p, 2);
            p += __shfl_xor(p, 4);
            if (fl == 0) out[e0 + k] = p + bout0;
        }
    }
}

extern "C" void kernel_launch(void* const* d_in, const int* in_sizes, int n_in,
                              void* d_out, int out_size, void* d_ws, size_t ws_size,
                              hipStream_t stream) {
    const float* x    = (const float*)d_in[0];
    const int*   ei   = (const int*)d_in[1];   // int64 in reference -> int32 here
    const float* W1   = (const float*)d_in[2];
    const float* b1   = (const float*)d_in[3];
    const float* W2   = (const float*)d_in[4];
    const float* b2   = (const float*)d_in[5];
    const float* Wout = (const float*)d_in[6];
    const float* bout = (const float*)d_in[7];
    const int*   row0 = ei;        // edge_index[0] (source)
    const int*   col0 = ei + EE;   // edge_index[1] (destination)

    char* ws = (char*)d_ws;
    auto align = [](size_t v) { return (v + 255) / 256 * 256; };
    const size_t nInt = align((size_t)NN * 4);
    float* dinv    = (float*)ws;                 ws += nInt;
    int*   degi    = (int*)ws;                   ws += nInt;
    int*   starts  = (int*)ws;                   ws += nInt;
    int*   bcnt    = (int*)ws;                   ws += align((size_t)NB * 4);
    int*   csr_src = (int*)ws;                   ws += align((size_t)NB * CAP * 4);
    uint4* bufH    = (uint4*)ws;                 ws += align((size_t)NN * FHID * 2);
    uint4* bufY    = (uint4*)ws;                 ws += align((size_t)NN * FHID * 2);
    // rec (19.2 MB) aliases bufH+bufY (25.6 MB): dead before k_gemm1 writes bufH
    unsigned long long* rec = (unsigned long long*)bufH;
    float* out = (float*)d_out;

    const int nTiles = (NN + 63) / 64;  // 1563

    // CSR build: zero (async memset) -> bin -> finalize
    hipMemsetAsync(bcnt, 0, (size_t)NB * 4, stream);
    k_bin<<<BIN_BLOCKS, 1024, 0, stream>>>(row0, col0, bcnt, rec);
    k_csr<<<NB, 256, 0, stream>>>(bcnt, rec, csr_src, starts, degi, dinv);

    // layer 1: hs1 = (x@W1)*dinv ; y1 = relu(dinv*gather(hs1) + b1)
    k_gemm1<<<nTiles, 512, 0, stream>>>(x, W1, dinv, bufH);
    k_gath<<<(NN + 31) / 32, 256, 0, stream>>>(starts, degi, csr_src, dinv, bufH, b1, bufY);

    // layer 2: hs2 = (y1@W2)*dinv ; y2 = relu(dinv*gather(hs2) + b2)
    k_gemm2<<<nTiles, 256, 0, stream>>>((const uint2*)bufY, W2, dinv, bufH);
    k_gath<<<(NN + 31) / 32, 256, 0, stream>>>(starts, degi, csr_src, dinv, bufH, b2, bufY);

    // edge scoring in original edge order (coalesced reads + writes)
    k_link<<<2048, 256, 0, stream>>>(row0, col0, bufY, Wout, bout, out);
}

// Round 16
// 201.405 us; speedup vs baseline: 1.0732x; 1.0048x over previous
//
#include <hip/hip_runtime.h>

#define NN 100000
#define EE 1600000
#define FIN 128
#define FHID 64

#define BSH 7                       // bucket = node >> 7 (128 nodes/bucket)
#define NB  ((NN + 127) / 128)      // 782 buckets
#define CAP 3072                    // max edges/bucket (mean 2048, +22 sigma)
#define BIN_BLOCKS 256
#define BIN_EPT 8
#define BIN_EPB (1024 * BIN_EPT)    // 8192 edges/block

typedef union { _Float16 h[4]; uint2 u; } H4;
typedef union { _Float16 h[8]; uint4 u; } H8;

// ---------- pass 1: bin edges by dest bucket; dense chunk writes of
//            packed u32 (cl:7 | r:17) records ----------
__global__ __launch_bounds__(1024) void k_bin(const int* __restrict__ row,
                                              const int* __restrict__ col,
                                              int* __restrict__ bcnt,
                                              unsigned* __restrict__ rec) {
    __shared__ int hist[NB];
    __shared__ int base[NB];
    int tid = threadIdx.x;
    for (int i = tid; i < NB; i += 1024) hist[i] = 0;
    __syncthreads();
    int e0 = blockIdx.x * BIN_EPB;
    int b[BIN_EPT];
    int rnk[BIN_EPT];
    unsigned pk[BIN_EPT];
#pragma unroll
    for (int j = 0; j < BIN_EPT; ++j) {
        int e = e0 + j * 1024 + tid;
        b[j] = -1;
        if (e < EE) {
            int c = col[e];
            int r = row[e];
            b[j] = c >> BSH;
            pk[j] = ((unsigned)(c & 127) << 17) | (unsigned)r;
            rnk[j] = atomicAdd(&hist[b[j]], 1);
        }
    }
    __syncthreads();
    for (int i = tid; i < NB; i += 1024) {
        int h = hist[i];
        base[i] = h ? atomicAdd(&bcnt[i], h) : 0;
    }
    __syncthreads();
#pragma unroll
    for (int j = 0; j < BIN_EPT; ++j) {
        if (b[j] >= 0) {
            int p = base[b[j]] + rnk[j];
            if (p < CAP) rec[(size_t)b[j] * CAP + p] = pk[j];
        }
    }
}

// ---------- pass 2: per-bucket CSR finalize (fixed stride b*CAP);
//            emits csr_src, starts, degi, dinv ----------
__global__ __launch_bounds__(256) void k_csr(const int* __restrict__ bcnt,
                                             const unsigned* __restrict__ rec,
                                             int* __restrict__ csr_src,
                                             int* __restrict__ starts,
                                             int* __restrict__ degi,
                                             float* __restrict__ dinv) {
    __shared__ unsigned short rank[CAP];   // 6 KB
    __shared__ int nh[128];
    __shared__ int ns[128];
    __shared__ int nsx[128];
    int b = blockIdx.x;
    int tid = threadIdx.x;
    int cnt = bcnt[b];
    if (cnt > CAP) cnt = CAP;
    int gb = b * CAP;
    const unsigned* r = rec + (size_t)b * CAP;
    if (tid < 128) nh[tid] = 0;
    __syncthreads();
    for (int i = tid; i < cnt; i += 256) {
        int cl = (int)(r[i] >> 17);
        rank[i] = (unsigned short)atomicAdd(&nh[cl], 1);
    }
    __syncthreads();
    if (tid < 128) ns[tid] = nh[tid];
    __syncthreads();
    for (int off = 1; off < 128; off <<= 1) {
        int x = 0;
        if (tid < 128 && tid >= off) x = ns[tid - off];
        __syncthreads();
        if (tid < 128) ns[tid] += x;
        __syncthreads();
    }
    if (tid < 128) {
        int excl = ns[tid] - nh[tid];
        nsx[tid] = excl;
        int n = (b << BSH) + tid;
        if (n < NN) {
            starts[n] = gb + excl;
            degi[n] = nh[tid];
            dinv[n] = rsqrtf((float)(nh[tid] + 1));   // +1 self-loop
        }
    }
    __syncthreads();
    for (int i = tid; i < cnt; i += 256) {
        unsigned rv = r[i];
        int cl = (int)(rv >> 17);
        csr_src[gb + nsx[cl] + (int)rank[i]] = (int)(rv & 0x1FFFF);
    }
}

// ---------- GEMM1: hs16 = fp16((x @ W1) * dinv) ----------
// 512 threads = 8 waves; wave w computes cols [w*8, w*8+8) for 64 nodes
// (lane = node) -> 4 blocks x 8 waves = 32 waves/CU (max occupancy).
#define XPAD 129
__global__ __launch_bounds__(512) void k_gemm1(const float* __restrict__ x,
                                               const float* __restrict__ W1,
                                               const float* __restrict__ dinv,
                                               uint4* __restrict__ hs16) {
    __shared__ float xl[64 * XPAD];  // 33 KB
    int tid = threadIdx.x;
    int n0 = blockIdx.x * 64;
    const float4* x4 = reinterpret_cast<const float4*>(x);
#pragma unroll
    for (int i = 0; i < 4; ++i) {
        int idx = i * 512 + tid;     // 2048 float4 slots = 64 rows x 32
        int row = idx >> 5;
        int k4 = idx & 31;
        float4 v = {0.f, 0.f, 0.f, 0.f};
        if (n0 + row < NN) v = x4[(size_t)(n0 + row) * 32 + k4];
        float* p = &xl[row * XPAD + k4];   // perm(k4*4+j) = j*32 + k4
        p[0] = v.x; p[32] = v.y; p[64] = v.z; p[96] = v.w;
    }
    __syncthreads();

    int wv = __builtin_amdgcn_readfirstlane(tid >> 6);   // 0..7
    int lane = tid & 63;
    float acc[8];
#pragma unroll
    for (int c = 0; c < 8; ++c) acc[c] = 0.f;
    const float* Wb = W1 + wv * 8;
    const float* xrow = &xl[lane * XPAD];
#pragma unroll 8
    for (int k = 0; k < FIN; ++k) {
        float xk = xrow[((k & 3) << 5) | (k >> 2)];
        const float* wr = Wb + k * FHID;
#pragma unroll
        for (int c = 0; c < 8; ++c) acc[c] = fmaf(xk, wr[c], acc[c]);
    }

    int node = n0 + lane;
    if (node < NN) {
        float dn = dinv[node];
        H8 pk;
#pragma unroll
        for (int c = 0; c < 8; ++c) pk.h[c] = (_Float16)(acc[c] * dn);
        hs16[(size_t)node * 8 + wv] = pk.u;
    }
}

// ---------- GEMM2: hs16 = fp16((y1 @ W2) * dinv), y1 already relu'd fp16 ----------
#define X2PAD 65
typedef union { _Float16 h[16]; uint4 u[2]; } H16;
__global__ __launch_bounds__(256) void k_gemm2(const uint2* __restrict__ y1,
                                               const float* __restrict__ W2,
                                               const float* __restrict__ dinv,
                                               uint4* __restrict__ hs16) {
    __shared__ float al[64 * X2PAD];  // 16.6 KB
    int tid = threadIdx.x;
    int n0 = blockIdx.x * 64;
#pragma unroll
    for (int i = 0; i < 4; ++i) {
        int idx = i * 256 + tid;     // 1024 uint2 slots = 64 rows x 16
        int rw = idx >> 4;
        int k4 = idx & 15;
        float4 v = {0.f, 0.f, 0.f, 0.f};
        if (n0 + rw < NN) {
            H4 t;
            t.u = y1[(size_t)(n0 + rw) * 16 + k4];
            v.x = (float)t.h[0]; v.y = (float)t.h[1];
            v.z = (float)t.h[2]; v.w = (float)t.h[3];
        }
        float* p = &al[rw * X2PAD + k4];  // perm(k4*4+j) = j*16 + k4
        p[0] = v.x; p[16] = v.y; p[32] = v.z; p[48] = v.w;
    }
    __syncthreads();

    int wv = __builtin_amdgcn_readfirstlane(tid >> 6);
    int lane = tid & 63;
    float acc[16];
#pragma unroll
    for (int c = 0; c < 16; ++c) acc[c] = 0.f;
    const float* Wb = W2 + wv * 16;
    const float* arow = &al[lane * X2PAD];
#pragma unroll 8
    for (int k = 0; k < FHID; ++k) {
        float xk = arow[((k & 3) << 4) | (k >> 2)];
        const float* wr = Wb + k * FHID;
#pragma unroll
        for (int c = 0; c < 16; ++c) acc[c] = fmaf(xk, wr[c], acc[c]);
    }

    int node = n0 + lane;
    if (node < NN) {
        float dn = dinv[node];
        H16 pk;
#pragma unroll
        for (int c = 0; c < 16; ++c) pk.h[c] = (_Float16)(acc[c] * dn);
        hs16[(size_t)node * 8 + wv * 2] = pk.u[0];
        hs16[(size_t)node * 8 + wv * 2 + 1] = pk.u[1];
    }
}

// ---------- CSR aggregation: y[n] = fp16(relu(dinv[n]*(h[n]+sum h[src]) + bias)) ----------
// One 8-lane GROUP per node (8 nodes/wave): per-feature sums stay inside the
// group -> NO cross-group reduce, epilogue on all lanes. Indices preloaded
// 24-deep (coalesced) and broadcast via intra-group shfl; full-8 chunks
// unrolled so 8 gathers issue back-to-back.
#define GCHUNK8(IDXREG)                                                     \
    {                                                                       \
        H8 v0, v1, v2, v3, v4, v5, v6, v7;                                  \
        v0.u = hIn[(size_t)__shfl(IDXREG, base + 0) * 8 + fl];              \
        v1.u = hIn[(size_t)__shfl(IDXREG, base + 1) * 8 + fl];              \
        v2.u = hIn[(size_t)__shfl(IDXREG, base + 2) * 8 + fl];              \
        v3.u = hIn[(size_t)__shfl(IDXREG, base + 3) * 8 + fl];              \
        v4.u = hIn[(size_t)__shfl(IDXREG, base + 4) * 8 + fl];              \
        v5.u = hIn[(size_t)__shfl(IDXREG, base + 5) * 8 + fl];              \
        v6.u = hIn[(size_t)__shfl(IDXREG, base + 6) * 8 + fl];              \
        v7.u = hIn[(size_t)__shfl(IDXREG, base + 7) * 8 + fl];              \
        _Pragma("unroll")                                                   \
        for (int j = 0; j < 8; ++j)                                         \
            a[j] += ((float)v0.h[j] + (float)v1.h[j]) +                     \
                    ((float)v2.h[j] + (float)v3.h[j]) +                     \
                    ((float)v4.h[j] + (float)v5.h[j]) +                     \
                    ((float)v6.h[j] + (float)v7.h[j]);                      \
    }

__global__ __launch_bounds__(256) void k_gath(const int* __restrict__ starts,
                                              const int* __restrict__ degi,
                                              const int* __restrict__ csr_src,
                                              const float* __restrict__ dinv,
                                              const uint4* __restrict__ hIn,
                                              const float* __restrict__ bias,
                                              uint4* __restrict__ yOut) {
    int wave = threadIdx.x >> 6;
    int lane = threadIdx.x & 63;
    int g = lane >> 3;        // group = node slot 0..7
    int fl = lane & 7;        // 16B chunk 0..7
    int base = lane & 56;     // g*8 (shfl source base within wave)
    int n = blockIdx.x * 32 + wave * 8 + g;
    if (n >= NN) return;
    int s = starts[n];
    int d = degi[n];
    // preload up to 24 indices (covers ~98% of Poisson(16) nodes fully)
    int ia = (fl < d)      ? csr_src[s + fl]      : 0;
    int ib = (8 + fl < d)  ? csr_src[s + 8 + fl]  : 0;
    int ic = (16 + fl < d) ? csr_src[s + 16 + fl] : 0;
    float a[8];
    H8 pk;
    pk.u = hIn[(size_t)n * 8 + fl];   // self term
#pragma unroll
    for (int j = 0; j < 8; ++j) a[j] = (float)pk.h[j];

    int k = 0;
    if (d >= 8)  { GCHUNK8(ia); k = 8; }
    if (d >= 16) { GCHUNK8(ib); k = 16; }
    if (d >= 24) { GCHUNK8(ic); k = 24; }
    // leftover inside preloaded registers ([k, min(d,24)))
    int lim = d < 24 ? d : 24;
    for (; k < lim; ++k) {
        int k8 = k >> 3;
        int src = (k8 == 0) ? ia : ((k8 == 1) ? ib : ic);
        H8 v;
        v.u = hIn[(size_t)__shfl(src, base + (k & 7)) * 8 + fl];
#pragma unroll
        for (int j = 0; j < 8; ++j) a[j] += (float)v.h[j];
    }
    for (; k < d; ++k) {              // rare deg>24 tail: direct index load
        H8 v;
        v.u = hIn[(size_t)csr_src[s + k] * 8 + fl];
#pragma unroll
        for (int j = 0; j < 8; ++j) a[j] += (float)v.h[j];
    }

    float dn = dinv[n];
    float4 b0 = reinterpret_cast<const float4*>(bias)[fl * 2];
    float4 b1 = reinterpret_cast<const float4*>(bias)[fl * 2 + 1];
    H8 o;
    o.h[0] = (_Float16)fmaxf(fmaf(a[0], dn, b0.x), 0.f);
    o.h[1] = (_Float16)fmaxf(fmaf(a[1], dn, b0.y), 0.f);
    o.h[2] = (_Float16)fmaxf(fmaf(a[2], dn, b0.z), 0.f);
    o.h[3] = (_Float16)fmaxf(fmaf(a[3], dn, b0.w), 0.f);
    o.h[4] = (_Float16)fmaxf(fmaf(a[4], dn, b1.x), 0.f);
    o.h[5] = (_Float16)fmaxf(fmaf(a[5], dn, b1.y), 0.f);
    o.h[6] = (_Float16)fmaxf(fmaf(a[6], dn, b1.z), 0.f);
    o.h[7] = (_Float16)fmaxf(fmaf(a[7], dn, b1.w), 0.f);
    yOut[(size_t)n * 8 + fl] = o.u;
}

// ---------- link prediction: 64-edge batches/wave; indices preloaded
//            coalesced and broadcast via shfl; 8 edges x 8 lanes per iter ----------
__global__ __launch_bounds__(256) void k_link(const int* __restrict__ row0,
                                              const int* __restrict__ col0,
                                              const uint4* __restrict__ y16,
                                              const float* __restrict__ Wout,
                                              const float* __restrict__ bout,
                                              float* __restrict__ out) {
    int wid = blockIdx.x * 4 + (threadIdx.x >> 6);
    int lane = threadIdx.x & 63;
    int sub = lane >> 3;      // edge slot within iteration 0..7
    int fl = lane & 7;
    float4 w0 = reinterpret_cast<const float4*>(Wout)[fl * 2];
    float4 w1 = reinterpret_cast<const float4*>(Wout)[fl * 2 + 1];
    float wv[8] = {w0.x, w0.y, w0.z, w0.w, w1.x, w1.y, w1.z, w1.w};
    float bout0 = bout[0];
    const int NBATCH = EE / 64;    // 25000
    int stride = gridDim.x * 4;
    for (int q = wid; q < NBATCH; q += stride) {
        int e0 = q * 64;
        int r64 = row0[e0 + lane];   // one coalesced load each
        int c64 = col0[e0 + lane];
#pragma unroll
        for (int it = 0; it < 8; ++it) {
            int k = it * 8 + sub;
            int r = __shfl(r64, k);
            int c = __shfl(c64, k);
            H8 hr, hc;
            hr.u = y16[(size_t)r * 8 + fl];
            hc.u = y16[(size_t)c * 8 + fl];
            float p = 0.f;
#pragma unroll
            for (int j = 0; j < 8; ++j)
                p = fmaf((float)hr.h[j], (float)hc.h[j] * wv[j], p);
            p += __shfl_xor(p, 1);
            p += __shfl_xor(p, 2);
            p += __shfl_xor(p, 4);
            if (fl == 0) out[e0 + k] = p + bout0;
        }
    }
}

extern "C" void kernel_launch(void* const* d_in, const int* in_sizes, int n_in,
                              void* d_out, int out_size, void* d_ws, size_t ws_size,
                              hipStream_t stream) {
    const float* x    = (const float*)d_in[0];
    const int*   ei   = (const int*)d_in[1];   // int64 in reference -> int32 here
    const float* W1   = (const float*)d_in[2];
    const float* b1   = (const float*)d_in[3];
    const float* W2   = (const float*)d_in[4];
    const float* b2   = (const float*)d_in[5];
    const float* Wout = (const float*)d_in[6];
    const float* bout = (const float*)d_in[7];
    const int*   row0 = ei;        // edge_index[0] (source)
    const int*   col0 = ei + EE;   // edge_index[1] (destination)

    char* ws = (char*)d_ws;
    auto align = [](size_t v) { return (v + 255) / 256 * 256; };
    const size_t nInt = align((size_t)NN * 4);
    float* dinv    = (float*)ws;                 ws += nInt;
    int*   degi    = (int*)ws;                   ws += nInt;
    int*   starts  = (int*)ws;                   ws += nInt;
    int*   bcnt    = (int*)ws;                   ws += align((size_t)NB * 4);
    int*   csr_src = (int*)ws;                   ws += align((size_t)NB * CAP * 4);
    uint4* bufH    = (uint4*)ws;                 ws += align((size_t)NN * FHID * 2);
    uint4* bufY    = (uint4*)ws;                 ws += align((size_t)NN * FHID * 2);
    // rec (9.6 MB u32) aliases bufH (12.8 MB): dead before k_gemm1 writes bufH
    unsigned* rec = (unsigned*)bufH;
    float* out = (float*)d_out;

    const int nTiles = (NN + 63) / 64;  // 1563

    // CSR build: zero (async memset) -> bin -> finalize
    hipMemsetAsync(bcnt, 0, (size_t)NB * 4, stream);
    k_bin<<<BIN_BLOCKS, 1024, 0, stream>>>(row0, col0, bcnt, rec);
    k_csr<<<NB, 256, 0, stream>>>(bcnt, rec, csr_src, starts, degi, dinv);

    // layer 1: hs1 = (x@W1)*dinv ; y1 = relu(dinv*gather(hs1) + b1)
    k_gemm1<<<nTiles, 512, 0, stream>>>(x, W1, dinv, bufH);
    k_gath<<<(NN + 31) / 32, 256, 0, stream>>>(starts, degi, csr_src, dinv, bufH, b1, bufY);

    // layer 2: hs2 = (y1@W2)*dinv ; y2 = relu(dinv*gather(hs2) + b2)
    k_gemm2<<<nTiles, 256, 0, stream>>>((const uint2*)bufY, W2, dinv, bufH);
    k_gath<<<(NN + 31) / 32, 256, 0, stream>>>(starts, degi, csr_src, dinv, bufH, b2, bufY);

    // edge scoring in original edge order (coalesced reads + writes)
    k_link<<<2048, 256, 0, stream>>>(row0, col0, bufY, Wout, bout, out);
}